// Round 7
// baseline (614.174 us; speedup 1.0000x reference)
//
#include <hip/hip_runtime.h>

// CrossAttention: B=4, L=256, D=2048, LE=2048, DE=1024, H=16, HD=128
// R7: (a) KV projection in a dedicated 512-thread 256x128-tile GEMM
//     (8 waves/block, dbuf 48KB LDS -> 3 blocks/CU = 24 waves/CU) with the
//     V half written out TRANSPOSED (Vt) straight from the epilogue;
//     (b) transpose_bf16_batched kernel eliminated;
//     (c) gemm_bt reverted to R3's simple single-barrier dbuf loop (32KB).

#define B_ 4
#define L_ 256
#define D_ 2048
#define LE_ 2048
#define DE_ 1024
#define H_ 16
#define HD_ 128

using f32x4  = __attribute__((ext_vector_type(4))) float;
using bf16x8 = __attribute__((ext_vector_type(8))) short;

__device__ __forceinline__ unsigned short f2bf(float f) {
    union { float f; unsigned int u; } v; v.f = f;
    unsigned int r = v.u + 0x7fffu + ((v.u >> 16) & 1u);   // RNE
    return (unsigned short)(r >> 16);
}
__device__ __forceinline__ float b2f(unsigned short h) {
    union { unsigned int u; float f; } v; v.u = ((unsigned int)h) << 16;
    return v.f;
}

__device__ __forceinline__ void load_lds16(const void* g, void* l) {
    __builtin_amdgcn_global_load_lds((const __attribute__((address_space(1))) void*)g,
                                     (__attribute__((address_space(3))) void*)l, 16, 0, 0);
}

// ---------------- elementwise cast fp32 -> bf16 (vec4) ----------------
__global__ void cast_f32_bf16(const float* __restrict__ in, unsigned short* __restrict__ out, int n) {
    int i = (blockIdx.x * 256 + threadIdx.x) * 4;
    if (i < n) {
        float4 v = *(const float4*)(in + i);
        ushort4 o;
        o.x = f2bf(v.x); o.y = f2bf(v.y); o.z = f2bf(v.z); o.w = f2bf(v.w);
        *(ushort4*)(out + i) = o;
    }
}

// ---------------- tiled transpose fp32[R,C] -> bf16[C,R] ----------------
__global__ void transpose_f32_bf16(const float* __restrict__ in, unsigned short* __restrict__ out,
                                   int R, int C) {
    __shared__ float t[32][33];
    int r0 = blockIdx.y * 32, c0 = blockIdx.x * 32;
    int tx = threadIdx.x, ty = threadIdx.y;            // block (32,8)
    #pragma unroll
    for (int i = 0; i < 32; i += 8) t[ty + i][tx] = in[(long)(r0 + ty + i) * C + c0 + tx];
    __syncthreads();
    #pragma unroll
    for (int i = 0; i < 32; i += 8) out[(long)(c0 + ty + i) * R + r0 + tx] = f2bf(t[tx][ty + i]);
}

// ---------------- combine Q split-K=4 partials + bias + RoPE -> Q_bf head layout ----------------
__global__ void combine_q_rope(const float* __restrict__ P, const float* __restrict__ bq,
                               unsigned short* __restrict__ Q) {
    int gid = blockIdx.x * 256 + threadIdx.x;          // 1,048,576 pairs
    int p = gid & 63;
    int h = (gid >> 6) & 15;
    int m = gid >> 10;                                 // 0..1023
    int n = h * 128 + 2 * p;
    long i0 = (long)m * 2048 + n;
    float q1 = bq[n], q2 = bq[n + 1];
    #pragma unroll
    for (int pt = 0; pt < 4; pt++) {
        float2 a = *(const float2*)(P + (long)pt * 2097152 + i0);
        q1 += a.x; q2 += a.y;
    }
    int l = m & 255, b = m >> 8;
    float inv = powf(10000.0f, -(float)p * (1.0f / 64.0f));
    float s, c;
    sincosf((float)l * inv, &s, &c);
    const float sc = 0.08838834764831845f;             // 1/sqrt(128)
    long qi = (((long)(b * 16 + h) * 256 + l) << 7) + 2 * p;
    ushort2 o;
    o.x = f2bf((q1 * c - q2 * s) * sc);
    o.y = f2bf((q1 * s + q2 * c) * sc);
    *(ushort2*)(Q + qi) = o;
}

// ---------------- combine PV split-K=4 partials -> ctx_bf ----------------
__global__ void combine_pv(const float* __restrict__ P, unsigned short* __restrict__ ctx) {
    int gid = blockIdx.x * 256 + threadIdx.x;          // 524288 threads, 4 floats each
    long e = (long)gid * 4;
    float4 a = *(const float4*)(P + e);
    #pragma unroll
    for (int pt = 1; pt < 4; pt++) {
        float4 b = *(const float4*)(P + (long)pt * 2097152 + e);
        a.x += b.x; a.y += b.y; a.z += b.z; a.w += b.w;
    }
    int bh = (int)(e >> 15);
    int m  = (int)((e >> 7) & 255);
    int d  = (int)(e & 127);
    int bb = bh >> 4, h = bh & 15;
    ushort4 o;
    o.x = f2bf(a.x); o.y = f2bf(a.y); o.z = f2bf(a.z); o.w = f2bf(a.w);
    *(ushort4*)(ctx + ((long)(bb * 256 + m)) * 2048 + h * 128 + d) = o;
}

// ---------------- combine O split-K=4 partials + bias -> fp32 out ----------------
__global__ void combine_o(const float* __restrict__ P, const float* __restrict__ bo,
                          float* __restrict__ out) {
    int gid = blockIdx.x * 256 + threadIdx.x;          // 524288
    long e = (long)gid * 4;
    int n = (int)(e & 2047);
    float4 r = *(const float4*)(bo + n);
    #pragma unroll
    for (int pt = 0; pt < 4; pt++) {
        float4 a = *(const float4*)(P + (long)pt * 2097152 + e);
        r.x += a.x; r.y += a.y; r.z += a.z; r.w += a.w;
    }
    *(float4*)(out + e) = r;
}

// ---------------- row softmax, in-place on bf16 rows of 2048 (16B/thread) ----------------
__launch_bounds__(256)
__global__ void softmax_rows(unsigned short* __restrict__ S) {
    long row = blockIdx.x;
    unsigned short* p = S + row * 2048;
    int t = threadIdx.x, w = t >> 6, lane = t & 63;
    bf16x8 raw = *(const bf16x8*)(p + t * 8);
    float v[8];
    float mx = -1e30f;
    #pragma unroll
    for (int i = 0; i < 8; i++) { v[i] = b2f((unsigned short)raw[i]); mx = fmaxf(mx, v[i]); }
    #pragma unroll
    for (int o = 32; o; o >>= 1) mx = fmaxf(mx, __shfl_xor(mx, o));
    __shared__ float redm[4], reds[4];
    if (lane == 0) redm[w] = mx;
    __syncthreads();
    mx = fmaxf(fmaxf(redm[0], redm[1]), fmaxf(redm[2], redm[3]));
    float sum = 0.f;
    #pragma unroll
    for (int i = 0; i < 8; i++) { v[i] = __expf(v[i] - mx); sum += v[i]; }
    #pragma unroll
    for (int o = 32; o; o >>= 1) sum += __shfl_xor(sum, o);
    if (lane == 0) reds[w] = sum;
    __syncthreads();
    sum = reds[0] + reds[1] + reds[2] + reds[3];
    float r = 1.0f / sum;
    bf16x8 res;
    #pragma unroll
    for (int i = 0; i < 8; i++) res[i] = (short)f2bf(v[i] * r);
    *(bf16x8*)(p + t * 8) = res;
}

// ================= KV projection GEMM: 512 threads, 256x128 tile =================
// C[8192, 4096] = enc_bf[8192,1024] @ WkvT[4096,1024]^T + bias.
// n0 < 2048: K half -> K_bf [b*16+h][le][128] (+bk)
// n0 >= 2048: V half -> Vt  [b*16+h][d][2048] (+bv), TRANSPOSED in epilogue.
__launch_bounds__(512, 6)
__global__ void gemm_kv(const unsigned short* __restrict__ A, const unsigned short* __restrict__ Bt,
                        const float* __restrict__ bk, const float* __restrict__ bv,
                        unsigned short* __restrict__ Kout, unsigned short* __restrict__ Vt) {
    __shared__ __align__(16) unsigned short smem[24576];  // 48 KB: 2 stages x (A 16KB + B 8KB)
    const int lda = 1024, ldb = 1024, K = 1024;
    const int m0 = blockIdx.y * 256, n0 = blockIdx.x * 128;
    const int tid = threadIdx.x;
    const int w = tid >> 6, lane = tid & 63;
    const int quad = lane >> 4, l16 = lane & 15;
    const int wrow = w >> 1, wcol = w & 1;               // 4 m-quadrants x 2 n-halves
    const int srow = lane >> 2;
    const int scol = (lane & 3) * 8;

    f32x4 acc[4][4] = {};

    auto stage = [&](int k0, int p) {                    // 24 chunks / 8 waves = 3 each
        unsigned short* base = smem + p * 12288;
        #pragma unroll
        for (int q = 0; q < 3; q++) {
            int ci = w * 3 + q;                          // 0..23
            unsigned short* l = base + ci * 512;
            const unsigned short* g;
            if (ci < 16) g = A  + (long)(m0 + ci * 16 + srow) * lda + k0 + scol;
            else         g = Bt + (long)(n0 + (ci - 16) * 16 + srow) * ldb + k0 + scol;
            load_lds16(g, l);
        }
    };

    const int nk = K >> 5;                               // 32
    stage(0, 0);
    for (int i = 0; i < nk; i++) {
        __syncthreads();
        if (i + 1 < nk) stage((i + 1) << 5, (i + 1) & 1);
        const unsigned short* As = smem + (i & 1) * 12288;          // [256][32]
        const unsigned short* Bs = As + 8192;                       // [128][32]
        bf16x8 af[4], bfr[4];
        #pragma unroll
        for (int ii = 0; ii < 4; ii++) {
            int r = wrow * 64 + ii * 16 + l16;
            af[ii] = *(const bf16x8*)(As + r * 32 + quad * 8);
        }
        #pragma unroll
        for (int j = 0; j < 4; j++) {
            int r = wcol * 64 + j * 16 + l16;
            bfr[j] = *(const bf16x8*)(Bs + r * 32 + quad * 8);
        }
        #pragma unroll
        for (int ii = 0; ii < 4; ii++)
            #pragma unroll
            for (int j = 0; j < 4; j++)
                acc[ii][j] = __builtin_amdgcn_mfma_f32_16x16x32_bf16(af[ii], bfr[j], acc[ii][j], 0, 0, 0);
    }
    __syncthreads();

    const int b = m0 >> 11;                              // batch of this m-tile (256 | 2048)
    if (n0 < 2048) {
        // ---- K half: head relayout, 4 quarters of 64 m-rows ----
        const int h = n0 >> 7;
        #pragma unroll
        for (int qq = 0; qq < 4; qq++) {
            if (wrow == qq) {
                #pragma unroll
                for (int i = 0; i < 4; i++)
                    #pragma unroll
                    for (int j = 0; j < 4; j++)
                        #pragma unroll
                        for (int r = 0; r < 4; r++) {
                            int ml = i * 16 + quad * 4 + r;          // 0..63
                            int n  = wcol * 64 + j * 16 + l16;       // 0..127
                            smem[ml * 136 + n] = f2bf(acc[i][j][r] + bk[n0 + n]);
                        }
            }
            __syncthreads();
            #pragma unroll
            for (int pass = 0; pass < 2; pass++) {
                int row = pass * 32 + (tid >> 4);                    // 0..63
                int seg = tid & 15;
                bf16x8 val = *(const bf16x8*)(smem + row * 136 + seg * 8);
                int m = m0 + qq * 64 + row;
                int le = m & 2047;
                long idx = (((long)(b * 16 + h)) << 11) + le;
                *(bf16x8*)(Kout + (idx << 7) + seg * 8) = val;
            }
            __syncthreads();
        }
    } else {
        // ---- V half: write Vt[bh][d][le] via transposed bounce ----
        const int n0e = n0 - 2048;
        const int h = n0e >> 7;
        unsigned short* vbase = Vt + ((long)(b * 16 + h)) * (128 * 2048);
        #pragma unroll
        for (int qq = 0; qq < 4; qq++) {
            if (wrow == qq) {
                #pragma unroll
                for (int i = 0; i < 4; i++)
                    #pragma unroll
                    for (int j = 0; j < 4; j++) {
                        int d = wcol * 64 + j * 16 + l16;            // 0..127
                        #pragma unroll
                        for (int r = 0; r < 4; r++) {
                            int ml = i * 16 + quad * 4 + r;          // 0..63
                            smem[d * 72 + ml] = f2bf(acc[i][j][r] + bv[n0e + d]);
                        }
                    }
            }
            __syncthreads();
            #pragma unroll
            for (int pass = 0; pass < 4; pass++) {
                int d = pass * 32 + (tid >> 4);                      // 0..127
                int c = tid & 15;                                    // 4-elem group
                ushort4 val = *(const ushort4*)(smem + d * 72 + c * 4);
                int le = (m0 & 2047) + qq * 64 + c * 4;
                *(ushort4*)(vbase + (long)d * 2048 + le) = val;
            }
            __syncthreads();
        }
    }
}

// ---------------- bf16 GEMM (128x128, 4 waves): C = A[M,K] * Bt[N,K]^T ----------------
// R3 single-barrier dbuf loop. EPI 2: bf16 plain batched [z][M,N].
// EPI 4: fp32 split-K partial; z -> s=z/zdiv, bh=z%zdiv; out[(s*zdiv+bh)][M][N]
template <int EPI>
__launch_bounds__(256)
__global__ void gemm_bt(const unsigned short* __restrict__ A, const unsigned short* __restrict__ Bt,
                        void* __restrict__ outA,
                        int M, int N, int K, int lda, int ldb,
                        long strideA, long strideB, int zdiv) {
    __shared__ __align__(16) unsigned short smem[16384];  // 32 KB: 2 stages
    const int z = blockIdx.z;
    int s = 0, bh = z;
    if constexpr (EPI == 4) { s = z / zdiv; bh = z - s * zdiv; }
    const unsigned short* Ab = A + (long)bh * strideA + (long)s * K;
    const unsigned short* Bb = Bt + (long)bh * strideB + (long)s * K;
    const int m0 = blockIdx.y * 128, n0 = blockIdx.x * 128;
    const int tid = threadIdx.x;
    const int w = tid >> 6, lane = tid & 63;
    const int quad = lane >> 4, l16 = lane & 15;
    const int wr = w >> 1, wc = w & 1;
    const int srow = lane >> 2;
    const int scol = (lane & 3) * 8;

    f32x4 acc[4][4] = {};

    auto stage = [&](int k0, int p) {
        unsigned short* As = smem + p * 8192;
        unsigned short* Bs = As + 4096;
        #pragma unroll
        for (int q = 0; q < 2; q++) {
            int ci = q * 4 + w;
            int row = ci * 16 + srow;
            load_lds16(Ab + (long)(m0 + row) * lda + k0 + scol, (void*)(As + ci * 512));
            load_lds16(Bb + (long)(n0 + row) * ldb + k0 + scol, (void*)(Bs + ci * 512));
        }
    };

    const int nk = K >> 5;
    stage(0, 0);
    for (int i = 0; i < nk; i++) {
        __syncthreads();
        if (i + 1 < nk) stage((i + 1) << 5, (i + 1) & 1);
        const unsigned short* As = smem + (i & 1) * 8192;
        const unsigned short* Bs = As + 4096;
        bf16x8 af[4], bfr[4];
        #pragma unroll
        for (int ii = 0; ii < 4; ii++) {
            int r = wr * 64 + ii * 16 + l16;
            af[ii] = *(const bf16x8*)(As + r * 32 + quad * 8);
        }
        #pragma unroll
        for (int j = 0; j < 4; j++) {
            int r = wc * 64 + j * 16 + l16;
            bfr[j] = *(const bf16x8*)(Bs + r * 32 + quad * 8);
        }
        #pragma unroll
        for (int ii = 0; ii < 4; ii++)
            #pragma unroll
            for (int j = 0; j < 4; j++)
                acc[ii][j] = __builtin_amdgcn_mfma_f32_16x16x32_bf16(af[ii], bfr[j], acc[ii][j], 0, 0, 0);
    }
    __syncthreads();

    if constexpr (EPI == 2) {
        #pragma unroll
        for (int pp = 0; pp < 2; pp++) {
            if (wr == pp) {
                #pragma unroll
                for (int i = 0; i < 4; i++)
                    #pragma unroll
                    for (int j = 0; j < 4; j++)
                        #pragma unroll
                        for (int r = 0; r < 4; r++) {
                            int ml = i * 16 + quad * 4 + r;
                            int n  = wc * 64 + j * 16 + l16;
                            smem[ml * 136 + n] = f2bf(acc[i][j][r]);
                        }
            }
            __syncthreads();
            #pragma unroll
            for (int pass = 0; pass < 4; pass++) {
                int row = pass * 16 + (tid >> 4);
                int seg = tid & 15;
                bf16x8 val = *(const bf16x8*)(smem + row * 136 + seg * 8);
                int m = m0 + pp * 64 + row;
                *(bf16x8*)((unsigned short*)outA + (long)z * M * N + (long)m * N + n0 + seg * 8) = val;
            }
            __syncthreads();
        }
    } else {
        float* smf = (float*)smem;
        long zo = ((long)s * zdiv + bh) * (long)M * N;
        #pragma unroll
        for (int q4 = 0; q4 < 4; q4++) {
            if (wr == (q4 >> 1)) {
                #pragma unroll
                for (int ii = 0; ii < 2; ii++) {
                    int i = (q4 & 1) * 2 + ii;
                    #pragma unroll
                    for (int j = 0; j < 4; j++)
                        #pragma unroll
                        for (int r = 0; r < 4; r++) {
                            int ml = ii * 16 + quad * 4 + r;
                            int n  = wc * 64 + j * 16 + l16;
                            smf[ml * 132 + n] = acc[i][j][r];
                        }
                }
            }
            __syncthreads();
            #pragma unroll
            for (int pass = 0; pass < 4; pass++) {
                int row = pass * 8 + (tid >> 5);
                int seg = tid & 31;
                float4 val = *(const float4*)(smf + row * 132 + seg * 4);
                int m = m0 + q4 * 32 + row;
                *(float4*)((float*)outA + zo + (long)m * N + n0 + seg * 4) = val;
            }
            __syncthreads();
        }
    }
}

extern "C" void kernel_launch(void* const* d_in, const int* in_sizes, int n_in,
                              void* d_out, int out_size, void* d_ws, size_t ws_size,
                              hipStream_t stream) {
    const float* x   = (const float*)d_in[0];
    const float* enc = (const float*)d_in[1];
    const float* Wq  = (const float*)d_in[2];
    const float* bq  = (const float*)d_in[3];
    const float* Wk  = (const float*)d_in[4];
    const float* bk  = (const float*)d_in[5];
    const float* Wv  = (const float*)d_in[6];
    const float* bv  = (const float*)d_in[7];
    const float* Wo  = (const float*)d_in[8];
    const float* bo  = (const float*)d_in[9];
    float* out = (float*)d_out;

    // ws layout (MB offsets), liveness overlays:
    //   0: x_bf(4) | 4: enc_bf(16) | 20: WqT(8) | 28: WkvT(8) | 68: K_bf(32)
    // 100: WoT(8) | 108: Q_bf(4) | 112: Vt(64)
    //  Pq(32)@36  [free region 36..68; dead after combine_q]
    //  S_bf(64)@0 [x/enc/WqT/WkvT dead by S-GEMM]
    //  Ppv(32)@68 [K_bf dead after S-GEMM]
    //  Po(32)@0   [S_bf dead after PV]
    //  ctx_bf(4)@108 [Q_bf dead after S-GEMM]
    char* ws = (char*)d_ws;
    const size_t MB = 1024 * 1024;
    unsigned short* x_bf   = (unsigned short*)(ws + 0 * MB);
    unsigned short* enc_bf = (unsigned short*)(ws + 4 * MB);
    unsigned short* WqT    = (unsigned short*)(ws + 20 * MB);
    unsigned short* WkvT   = (unsigned short*)(ws + 28 * MB);
    unsigned short* K_bf   = (unsigned short*)(ws + 68 * MB);
    unsigned short* WoT    = (unsigned short*)(ws + 100 * MB);
    unsigned short* Q_bf   = (unsigned short*)(ws + 108 * MB);
    unsigned short* Vt     = (unsigned short*)(ws + 112 * MB);
    unsigned short* S_bf   = (unsigned short*)(ws + 0 * MB);
    float*          Pq     = (float*)(ws + 36 * MB);
    float*          Ppv    = (float*)(ws + 68 * MB);
    float*          Po     = (float*)(ws + 0 * MB);
    unsigned short* ctx_bf = (unsigned short*)(ws + 108 * MB);

    dim3 tb(32, 8);

    cast_f32_bf16<<<2048, 256, 0, stream>>>(x, x_bf, 2097152);
    cast_f32_bf16<<<8192, 256, 0, stream>>>(enc, enc_bf, 8388608);

    transpose_f32_bf16<<<dim3(64, 64), tb, 0, stream>>>(Wq, WqT, 2048, 2048);
    transpose_f32_bf16<<<dim3(64, 32), tb, 0, stream>>>(Wk, WkvT, 1024, 2048);
    transpose_f32_bf16<<<dim3(64, 32), tb, 0, stream>>>(Wv, WkvT + 2048 * 1024, 1024, 2048);
    transpose_f32_bf16<<<dim3(64, 64), tb, 0, stream>>>(Wo, WoT, 2048, 2048);

    // Q partials = x @ Wq, split-K=4 (K=512 each) -> Pq[4][1024][2048]
    gemm_bt<4><<<dim3(16, 8, 4), 256, 0, stream>>>(x_bf, WqT, Pq,
                                                   1024, 2048, 512, 2048, 2048, 0, 0, 1);
    combine_q_rope<<<4096, 256, 0, stream>>>(Pq, bq, Q_bf);

    // K|V = enc @ [Wk|Wv] + bias -> K_bf head layout, Vt transposed head layout
    gemm_kv<<<dim3(32, 32, 1), 512, 0, stream>>>(enc_bf, WkvT, bk, bv, K_bf, Vt);

    // S = Q @ K^T (scale folded into Q) -> bf16 [64][256][2048]
    gemm_bt<2><<<dim3(16, 2, 64), 256, 0, stream>>>(Q_bf, K_bf, S_bf,
                                                    256, 2048, 128, 128, 128,
                                                    256 * 128, 2048 * 128, 1);
    softmax_rows<<<16384, 256, 0, stream>>>(S_bf);

    // ctx partials = P @ V, split-K=4 (K=512 each): z = s*64+bh -> Ppv[4][64][256][128]
    gemm_bt<4><<<dim3(1, 2, 256), 256, 0, stream>>>(S_bf, Vt, Ppv,
                                                    256, 128, 512, 2048, 2048,
                                                    256 * 2048, 128 * 2048, 64);
    combine_pv<<<2048, 256, 0, stream>>>(Ppv, ctx_bf);

    // O partials = ctx @ Wo, split-K=4 (K=512 each) -> Po[4][1024][2048]
    gemm_bt<4><<<dim3(16, 8, 4), 256, 0, stream>>>(ctx_bf, WoT, Po,
                                                   1024, 2048, 512, 2048, 2048, 0, 0, 1);
    combine_o<<<2048, 256, 0, stream>>>(Po, bo, out);
}

// Round 8
// 362.866 us; speedup vs baseline: 1.6926x; 1.6926x over previous
//
#include <hip/hip_runtime.h>

// CrossAttention: B=4, L=256, D=2048, LE=2048, DE=1024, H=16, HD=128
// R8 = R6 baseline (406us) +
//   (a) V half of the KV GEMM written TRANSPOSED (Vt) directly from the
//       epilogue of the proven 256-thread gemm_bt -> transpose kernel gone;
//   (b) 4 weight transposes fused into 1 dispatch; 2 casts fused into 1.
// R7 lesson: __launch_bounds__ min-waves arg caps VGPRs; 512-thread/6-wave
// variant spilled the 64 acc VGPRs to scratch (534MB writes). Reverted.

#define B_ 4
#define L_ 256
#define D_ 2048
#define LE_ 2048
#define DE_ 1024
#define H_ 16
#define HD_ 128

using f32x4  = __attribute__((ext_vector_type(4))) float;
using bf16x8 = __attribute__((ext_vector_type(8))) short;

__device__ __forceinline__ unsigned short f2bf(float f) {
    union { float f; unsigned int u; } v; v.f = f;
    unsigned int r = v.u + 0x7fffu + ((v.u >> 16) & 1u);   // RNE
    return (unsigned short)(r >> 16);
}
__device__ __forceinline__ float b2f(unsigned short h) {
    union { unsigned int u; float f; } v; v.u = ((unsigned int)h) << 16;
    return v.f;
}

__device__ __forceinline__ void load_lds16(const void* g, void* l) {
    __builtin_amdgcn_global_load_lds((const __attribute__((address_space(1))) void*)g,
                                     (__attribute__((address_space(3))) void*)l, 16, 0, 0);
}

// ---------------- fused cast fp32 -> bf16 for x and enc ----------------
__global__ void cast_all(const float* __restrict__ x, const float* __restrict__ enc,
                         unsigned short* __restrict__ x_bf, unsigned short* __restrict__ enc_bf) {
    long i = (long)(blockIdx.x * 256 + threadIdx.x) * 4;   // 10,485,760 elements total
    const float* in;
    unsigned short* out;
    if (i < 2097152) { in = x + i; out = x_bf + i; }
    else             { in = enc + (i - 2097152); out = enc_bf + (i - 2097152); }
    float4 v = *(const float4*)in;
    ushort4 o;
    o.x = f2bf(v.x); o.y = f2bf(v.y); o.z = f2bf(v.z); o.w = f2bf(v.w);
    *(ushort4*)out = o;
}

// ---------------- fused weight transposes fp32[R,C] -> bf16[C,R], z-indexed ----------------
__global__ void transpose_weights(const float* __restrict__ Wq, const float* __restrict__ Wk,
                                  const float* __restrict__ Wv, const float* __restrict__ Wo,
                                  unsigned short* __restrict__ WqT, unsigned short* __restrict__ WkvT,
                                  unsigned short* __restrict__ WoT) {
    __shared__ float t[32][33];
    const float* in;
    unsigned short* out;
    int R;
    const int C = 2048;
    switch (blockIdx.z) {
        case 0:  in = Wq; out = WqT;                R = 2048; break;
        case 1:  in = Wk; out = WkvT;               R = 1024; break;
        case 2:  in = Wv; out = WkvT + 2048 * 1024; R = 1024; break;
        default: in = Wo; out = WoT;                R = 2048; break;
    }
    int r0 = blockIdx.y * 32, c0 = blockIdx.x * 32;
    if (r0 >= R) return;
    int tx = threadIdx.x, ty = threadIdx.y;            // block (32,8)
    #pragma unroll
    for (int i = 0; i < 32; i += 8) t[ty + i][tx] = in[(long)(r0 + ty + i) * C + c0 + tx];
    __syncthreads();
    #pragma unroll
    for (int i = 0; i < 32; i += 8) out[(long)(c0 + ty + i) * R + r0 + tx] = f2bf(t[tx][ty + i]);
}

// ---------------- combine Q split-K=4 partials + bias + RoPE -> Q_bf head layout ----------------
__global__ void combine_q_rope(const float* __restrict__ P, const float* __restrict__ bq,
                               unsigned short* __restrict__ Q) {
    int gid = blockIdx.x * 256 + threadIdx.x;          // 1,048,576 pairs
    int p = gid & 63;
    int h = (gid >> 6) & 15;
    int m = gid >> 10;                                 // 0..1023
    int n = h * 128 + 2 * p;
    long i0 = (long)m * 2048 + n;
    float q1 = bq[n], q2 = bq[n + 1];
    #pragma unroll
    for (int pt = 0; pt < 4; pt++) {
        float2 a = *(const float2*)(P + (long)pt * 2097152 + i0);
        q1 += a.x; q2 += a.y;
    }
    int l = m & 255, b = m >> 8;
    float inv = powf(10000.0f, -(float)p * (1.0f / 64.0f));
    float s, c;
    sincosf((float)l * inv, &s, &c);
    const float sc = 0.08838834764831845f;             // 1/sqrt(128)
    long qi = (((long)(b * 16 + h) * 256 + l) << 7) + 2 * p;
    ushort2 o;
    o.x = f2bf((q1 * c - q2 * s) * sc);
    o.y = f2bf((q1 * s + q2 * c) * sc);
    *(ushort2*)(Q + qi) = o;
}

// ---------------- combine PV split-K=4 partials -> ctx_bf ----------------
__global__ void combine_pv(const float* __restrict__ P, unsigned short* __restrict__ ctx) {
    int gid = blockIdx.x * 256 + threadIdx.x;          // 524288 threads, 4 floats each
    long e = (long)gid * 4;
    float4 a = *(const float4*)(P + e);
    #pragma unroll
    for (int pt = 1; pt < 4; pt++) {
        float4 b = *(const float4*)(P + (long)pt * 2097152 + e);
        a.x += b.x; a.y += b.y; a.z += b.z; a.w += b.w;
    }
    int bh = (int)(e >> 15);
    int m  = (int)((e >> 7) & 255);
    int d  = (int)(e & 127);
    int bb = bh >> 4, h = bh & 15;
    ushort4 o;
    o.x = f2bf(a.x); o.y = f2bf(a.y); o.z = f2bf(a.z); o.w = f2bf(a.w);
    *(ushort4*)(ctx + ((long)(bb * 256 + m)) * 2048 + h * 128 + d) = o;
}

// ---------------- combine O split-K=4 partials + bias -> fp32 out ----------------
__global__ void combine_o(const float* __restrict__ P, const float* __restrict__ bo,
                          float* __restrict__ out) {
    int gid = blockIdx.x * 256 + threadIdx.x;          // 524288
    long e = (long)gid * 4;
    int n = (int)(e & 2047);
    float4 r = *(const float4*)(bo + n);
    #pragma unroll
    for (int pt = 0; pt < 4; pt++) {
        float4 a = *(const float4*)(P + (long)pt * 2097152 + e);
        r.x += a.x; r.y += a.y; r.z += a.z; r.w += a.w;
    }
    *(float4*)(out + e) = r;
}

// ---------------- row softmax, in-place on bf16 rows of 2048 (16B/thread) ----------------
__launch_bounds__(256)
__global__ void softmax_rows(unsigned short* __restrict__ S) {
    long row = blockIdx.x;
    unsigned short* p = S + row * 2048;
    int t = threadIdx.x, w = t >> 6, lane = t & 63;
    bf16x8 raw = *(const bf16x8*)(p + t * 8);
    float v[8];
    float mx = -1e30f;
    #pragma unroll
    for (int i = 0; i < 8; i++) { v[i] = b2f((unsigned short)raw[i]); mx = fmaxf(mx, v[i]); }
    #pragma unroll
    for (int o = 32; o; o >>= 1) mx = fmaxf(mx, __shfl_xor(mx, o));
    __shared__ float redm[4], reds[4];
    if (lane == 0) redm[w] = mx;
    __syncthreads();
    mx = fmaxf(fmaxf(redm[0], redm[1]), fmaxf(redm[2], redm[3]));
    float sum = 0.f;
    #pragma unroll
    for (int i = 0; i < 8; i++) { v[i] = __expf(v[i] - mx); sum += v[i]; }
    #pragma unroll
    for (int o = 32; o; o >>= 1) sum += __shfl_xor(sum, o);
    if (lane == 0) reds[w] = sum;
    __syncthreads();
    sum = reds[0] + reds[1] + reds[2] + reds[3];
    float r = 1.0f / sum;
    bf16x8 res;
    #pragma unroll
    for (int i = 0; i < 8; i++) res[i] = (short)f2bf(v[i] * r);
    *(bf16x8*)(p + t * 8) = res;
}

// ---------------- bf16 GEMM (128x128, 256 thr): C = A[M,K] * Bt[N,K]^T ----------------
// R3 single-barrier dbuf K-loop (proven 594-602 TF at these shapes).
// EPI 1: KV fused. n0 < nsplit: K half -> outA[b*16+h][le][128] + biasA.
//        n0 >= nsplit: V half -> outB (Vt) [b*16+h][d][2048] + biasB, written
//        TRANSPOSED via stride-72 LDS bounce (2-way bank conflicts max).
// EPI 2: bf16 plain batched [z][M,N]
// EPI 4: fp32 split-K partial; z -> s=z/zdiv, bh=z%zdiv; out[(s*zdiv+bh)][M][N]
template <int EPI>
__launch_bounds__(256)
__global__ void gemm_bt(const unsigned short* __restrict__ A, const unsigned short* __restrict__ Bt,
                        const float* __restrict__ biasA, const float* __restrict__ biasB,
                        void* __restrict__ outA, void* __restrict__ outB,
                        int M, int N, int K, int lda, int ldb,
                        long strideA, long strideB, int zdiv, int nsplit) {
    __shared__ __align__(16) unsigned short smem[16384];  // 32 KB: 2 stages
    const int z = blockIdx.z;
    int s = 0, bh = z;
    if constexpr (EPI == 4) { s = z / zdiv; bh = z - s * zdiv; }
    const unsigned short* Ab = A + (long)bh * strideA + (long)s * K;
    const unsigned short* Bb = Bt + (long)bh * strideB + (long)s * K;
    const int m0 = blockIdx.y * 128, n0 = blockIdx.x * 128;
    const int tid = threadIdx.x;
    const int w = tid >> 6, lane = tid & 63;
    const int quad = lane >> 4, l16 = lane & 15;
    const int wr = w >> 1, wc = w & 1;
    const int srow = lane >> 2;
    const int scol = (lane & 3) * 8;

    f32x4 acc[4][4] = {};

    auto stage = [&](int k0, int p) {
        unsigned short* As = smem + p * 8192;
        unsigned short* Bs = As + 4096;
        #pragma unroll
        for (int q = 0; q < 2; q++) {
            int ci = q * 4 + w;
            int row = ci * 16 + srow;
            load_lds16(Ab + (long)(m0 + row) * lda + k0 + scol, (void*)(As + ci * 512));
            load_lds16(Bb + (long)(n0 + row) * ldb + k0 + scol, (void*)(Bs + ci * 512));
        }
    };

    const int nk = K >> 5;
    stage(0, 0);
    for (int i = 0; i < nk; i++) {
        __syncthreads();
        if (i + 1 < nk) stage((i + 1) << 5, (i + 1) & 1);
        const unsigned short* As = smem + (i & 1) * 8192;
        const unsigned short* Bs = As + 4096;
        bf16x8 af[4], bfr[4];
        #pragma unroll
        for (int ii = 0; ii < 4; ii++) {
            int r = wr * 64 + ii * 16 + l16;
            af[ii] = *(const bf16x8*)(As + r * 32 + quad * 8);
        }
        #pragma unroll
        for (int j = 0; j < 4; j++) {
            int r = wc * 64 + j * 16 + l16;
            bfr[j] = *(const bf16x8*)(Bs + r * 32 + quad * 8);
        }
        #pragma unroll
        for (int ii = 0; ii < 4; ii++)
            #pragma unroll
            for (int j = 0; j < 4; j++)
                acc[ii][j] = __builtin_amdgcn_mfma_f32_16x16x32_bf16(af[ii], bfr[j], acc[ii][j], 0, 0, 0);
    }
    __syncthreads();

    if constexpr (EPI == 1) {
        const int b = m0 >> 11;                        // m = b*2048 + le
        const int le0 = m0 & 2047;
        if (n0 < nsplit) {
            // ---- K half: head relayout ----
            const int h = n0 >> 7;
            unsigned short* dst = (unsigned short*)outA + ((((long)(b * 16 + h)) << 11) << 7);
            #pragma unroll
            for (int pp = 0; pp < 2; pp++) {
                if (wr == pp) {
                    #pragma unroll
                    for (int i = 0; i < 4; i++)
                        #pragma unroll
                        for (int j = 0; j < 4; j++)
                            #pragma unroll
                            for (int r = 0; r < 4; r++) {
                                int ml = i * 16 + quad * 4 + r;      // 0..63
                                int n  = wc * 64 + j * 16 + l16;     // 0..127
                                smem[ml * 136 + n] = f2bf(acc[i][j][r] + biasA[n0 + n]);
                            }
                }
                __syncthreads();
                #pragma unroll
                for (int pass = 0; pass < 4; pass++) {
                    int row = pass * 16 + (tid >> 4);                // 0..63
                    int seg = tid & 15;
                    bf16x8 val = *(const bf16x8*)(smem + row * 136 + seg * 8);
                    long le = le0 + pp * 64 + row;
                    *(bf16x8*)(dst + (le << 7) + seg * 8) = val;
                }
                __syncthreads();
            }
        } else {
            // ---- V half: write Vt[bh][d][le] transposed ----
            const int n0e = n0 - nsplit;
            const int h = n0e >> 7;
            unsigned short* vbase = (unsigned short*)outB + ((long)(b * 16 + h)) * (128 * 2048);
            #pragma unroll
            for (int pp = 0; pp < 2; pp++) {
                if (wr == pp) {
                    #pragma unroll
                    for (int i = 0; i < 4; i++)
                        #pragma unroll
                        for (int j = 0; j < 4; j++) {
                            int d = wc * 64 + j * 16 + l16;          // 0..127
                            float bvd = biasB[n0e + d];
                            #pragma unroll
                            for (int r = 0; r < 4; r++) {
                                int ml = i * 16 + quad * 4 + r;      // 0..63
                                smem[d * 72 + ml] = f2bf(acc[i][j][r] + bvd);
                            }
                        }
                }
                __syncthreads();
                #pragma unroll
                for (int pass = 0; pass < 4; pass++) {
                    int d = pass * 32 + (tid >> 3);                  // 0..127
                    int c = tid & 7;                                 // 8-elem group
                    bf16x8 val = *(const bf16x8*)(smem + d * 72 + c * 8);
                    *(bf16x8*)(vbase + (long)d * 2048 + le0 + pp * 64 + c * 8) = val;
                }
                __syncthreads();
            }
        }
    } else if constexpr (EPI == 2) {
        #pragma unroll
        for (int pp = 0; pp < 2; pp++) {
            if (wr == pp) {
                #pragma unroll
                for (int i = 0; i < 4; i++)
                    #pragma unroll
                    for (int j = 0; j < 4; j++)
                        #pragma unroll
                        for (int r = 0; r < 4; r++) {
                            int ml = i * 16 + quad * 4 + r;
                            int n  = wc * 64 + j * 16 + l16;
                            smem[ml * 136 + n] = f2bf(acc[i][j][r]);
                        }
            }
            __syncthreads();
            #pragma unroll
            for (int pass = 0; pass < 4; pass++) {
                int row = pass * 16 + (tid >> 4);
                int seg = tid & 15;
                bf16x8 val = *(const bf16x8*)(smem + row * 136 + seg * 8);
                int m = m0 + pp * 64 + row;
                *(bf16x8*)((unsigned short*)outA + (long)z * M * N + (long)m * N + n0 + seg * 8) = val;
            }
            __syncthreads();
        }
    } else {
        float* smf = (float*)smem;
        long zo = ((long)s * zdiv + bh) * (long)M * N;
        #pragma unroll
        for (int q4 = 0; q4 < 4; q4++) {
            if (wr == (q4 >> 1)) {
                #pragma unroll
                for (int ii = 0; ii < 2; ii++) {
                    int i = (q4 & 1) * 2 + ii;
                    #pragma unroll
                    for (int j = 0; j < 4; j++)
                        #pragma unroll
                        for (int r = 0; r < 4; r++) {
                            int ml = ii * 16 + quad * 4 + r;
                            int n  = wc * 64 + j * 16 + l16;
                            smf[ml * 132 + n] = acc[i][j][r];
                        }
                }
            }
            __syncthreads();
            #pragma unroll
            for (int pass = 0; pass < 4; pass++) {
                int row = pass * 8 + (tid >> 5);
                int seg = tid & 31;
                float4 val = *(const float4*)(smf + row * 132 + seg * 4);
                int m = m0 + q4 * 32 + row;
                *(float4*)((float*)outA + zo + (long)m * N + n0 + seg * 4) = val;
            }
            __syncthreads();
        }
    }
}

extern "C" void kernel_launch(void* const* d_in, const int* in_sizes, int n_in,
                              void* d_out, int out_size, void* d_ws, size_t ws_size,
                              hipStream_t stream) {
    const float* x   = (const float*)d_in[0];
    const float* enc = (const float*)d_in[1];
    const float* Wq  = (const float*)d_in[2];
    const float* bq  = (const float*)d_in[3];
    const float* Wk  = (const float*)d_in[4];
    const float* bk  = (const float*)d_in[5];
    const float* Wv  = (const float*)d_in[6];
    const float* bv  = (const float*)d_in[7];
    const float* Wo  = (const float*)d_in[8];
    const float* bo  = (const float*)d_in[9];
    float* out = (float*)d_out;

    // ws layout (MB offsets), liveness overlays:
    //   0: x_bf(4) | 4: enc_bf(16) | 20: WqT(8) | 28: WkvT(8) | 68: K_bf(32)
    // 100: WoT(8) | 108: Q_bf(4) | 112: Vt(64)
    //  Pq(32)@36  [free region 36..68; dead after combine_q]
    //  S_bf(64)@0 [x/enc/WqT/WkvT dead by S-GEMM]
    //  Ppv(32)@68 [K_bf dead after S-GEMM]
    //  Po(32)@0   [S_bf dead after PV]
    //  ctx_bf(4)@108 [Q_bf dead after S-GEMM]
    char* ws = (char*)d_ws;
    const size_t MB = 1024 * 1024;
    unsigned short* x_bf   = (unsigned short*)(ws + 0 * MB);
    unsigned short* enc_bf = (unsigned short*)(ws + 4 * MB);
    unsigned short* WqT    = (unsigned short*)(ws + 20 * MB);
    unsigned short* WkvT   = (unsigned short*)(ws + 28 * MB);
    unsigned short* K_bf   = (unsigned short*)(ws + 68 * MB);
    unsigned short* WoT    = (unsigned short*)(ws + 100 * MB);
    unsigned short* Q_bf   = (unsigned short*)(ws + 108 * MB);
    unsigned short* Vt     = (unsigned short*)(ws + 112 * MB);
    unsigned short* S_bf   = (unsigned short*)(ws + 0 * MB);
    float*          Pq     = (float*)(ws + 36 * MB);
    float*          Ppv    = (float*)(ws + 68 * MB);
    float*          Po     = (float*)(ws + 0 * MB);
    unsigned short* ctx_bf = (unsigned short*)(ws + 108 * MB);

    // fused casts (x + enc)
    cast_all<<<10240, 256, 0, stream>>>(x, enc, x_bf, enc_bf);

    // fused weight transposes
    transpose_weights<<<dim3(64, 64, 4), dim3(32, 8), 0, stream>>>(Wq, Wk, Wv, Wo, WqT, WkvT, WoT);

    // Q partials = x @ Wq, split-K=4 (K=512 each) -> Pq[4][1024][2048]
    gemm_bt<4><<<dim3(16, 8, 4), 256, 0, stream>>>(x_bf, WqT, nullptr, nullptr, Pq, nullptr,
                                                   1024, 2048, 512, 2048, 2048, 0, 0, 1, 0);
    combine_q_rope<<<4096, 256, 0, stream>>>(Pq, bq, Q_bf);

    // K|V = enc @ [Wk|Wv] + bias -> K_bf head layout; V -> Vt transposed (epilogue)
    gemm_bt<1><<<dim3(32, 64, 1), 256, 0, stream>>>(enc_bf, WkvT, bk, bv, K_bf, Vt,
                                                    8192, 4096, 1024, 1024, 1024, 0, 0, 1, 2048);

    // S = Q @ K^T (scale folded into Q) -> bf16 [64][256][2048]
    gemm_bt<2><<<dim3(16, 2, 64), 256, 0, stream>>>(Q_bf, K_bf, nullptr, nullptr, S_bf, nullptr,
                                                    256, 2048, 128, 128, 128,
                                                    256 * 128, 2048 * 128, 1, 0);
    softmax_rows<<<16384, 256, 0, stream>>>(S_bf);

    // ctx partials = P @ V, split-K=4 (K=512 each): z = s*64+bh -> Ppv[4][64][256][128]
    gemm_bt<4><<<dim3(1, 2, 256), 256, 0, stream>>>(S_bf, Vt, nullptr, nullptr, Ppv, nullptr,
                                                    256, 128, 512, 2048, 2048,
                                                    256 * 2048, 128 * 2048, 64, 0);
    combine_pv<<<2048, 256, 0, stream>>>(Ppv, ctx_bf);

    // O partials = ctx @ Wo, split-K=4 (K=512 each) -> Po[4][1024][2048]
    gemm_bt<4><<<dim3(16, 8, 4), 256, 0, stream>>>(ctx_bf, WoT, nullptr, nullptr, Po, nullptr,
                                                   1024, 2048, 512, 2048, 2048, 0, 0, 1, 0);
    combine_o<<<2048, 256, 0, stream>>>(Po, bo, out);
}